// Round 25
// baseline (7081.993 us; speedup 1.0000x reference)
//
#include <hip/hip_runtime.h>

// All ops except the two deliberate FMAs below are per-op rounded.
#pragma clang fp contract(off)

#define BATCH 32
#define NPTS 100000
#define NGROUP 2048
#define NBLK_PER_BATCH 8
#define NPB (NPTS / NBLK_PER_BATCH)   /* 12500 points per block */
#define TPB 512
#define NPT 25                        /* staging: ceil(12500/512) writes/thread */
#define TAIL (NPB - (NPT - 1) * TPB)  /* 212 */
#define NQUAD 7                       /* compute: quads of 4 consecutive pts */
#define QTOT (NPB / 4)                /* 3125 quads, exact */
#define QTAIL (QTOT - (NQUAD - 1) * TPB) /* 53 */
#define NWAVE 64                      /* publishing waves per batch */

typedef unsigned long long u64;
typedef unsigned int u32;

static_assert(NPB * NBLK_PER_BATCH == NPTS, "block split must be exact");
static_assert(QTOT * 4 == NPB, "quad split must be exact");

__device__ __forceinline__ float fsub_x(float a, float b) {
  float r; asm("v_sub_f32 %0, %1, %2" : "=v"(r) : "v"(a), "v"(b)); return r;
}
__device__ __forceinline__ float fmul_x(float a, float b) {
  float r; asm("v_mul_f32 %0, %1, %2" : "=v"(r) : "v"(a), "v"(b)); return r;
}
__device__ __forceinline__ float fma_x(float a, float b, float c) {
  float r; asm("v_fma_f32 %0, %1, %2, %3" : "=v"(r) : "v"(a), "v"(b), "v"(c)); return r;
}

#define LD_WG(p)    __hip_atomic_load((p),  __ATOMIC_RELAXED, __HIP_MEMORY_SCOPE_WORKGROUP)
#define ST_WG(p,v)  __hip_atomic_store((p), (v), __ATOMIC_RELAXED, __HIP_MEMORY_SCOPE_WORKGROUP)
#define LD_AG(p)    __hip_atomic_load((p),  __ATOMIC_RELAXED, __HIP_MEMORY_SCOPE_AGENT)
#define ST_AG(p,v)  __hip_atomic_store((p), (v), __ATOMIC_RELAXED, __HIP_MEMORY_SCOPE_AGENT)

// R24 post-mortem: no single dominant term — the 2.4us iteration is a chain
// of coordination hops. This round removes the pre-publish tail (sval post +
// barrier + gather + block reduce): each of the 64 waves/batch publishes its
// wave candidate DIRECTLY to slots[b][parity][wave] after its wave reduce.
// wid0 polls all 64 (lane l <-> slot l), reduces, prefetches all 64 cand
// coords (hidden under reduce), selects, releases via 3 tagged LDS words.
// No barriers in the loop. 8 polling waves/batch (R13-proven; R21's blowup
// was 64 pollers). srel spins run only while wid0 polls globally — no
// compute concurrent -> R20's LDS-spin starvation doesn't apply.
// Slot: distbits[63:32] | tag[31:17] | ~idx[16:0]; memset 0xFF per call.
__global__ __launch_bounds__(TPB, 1)
void fps_kernel(const float* __restrict__ xyz,
                const int* __restrict__ finit,
                float* __restrict__ out,
                u64* __restrict__ slots)
{
  const int blk  = blockIdx.x;
  const int b    = blk & (BATCH - 1);   // batch id
  const int j    = blk >> 5;            // sub-block 0..7 within batch
  const int tid  = threadIdx.x;
  const int lane = tid & 63;
  const int wid  = tid >> 6;
  const int gw   = j * 8 + wid;         // global wave id in batch, 0..63

  __shared__ __align__(16) float sx[NPB];   // 50,000 B per plane
  __shared__ __align__(16) float sy[NPB];
  __shared__ __align__(16) float sz[NPB];
  __shared__ u64 srel[2][3];   // [parity][cx,cy,cz] tagged release words

  if (tid < 6) srel[tid / 3][tid % 3] = ~0ull;   // tag 0x7FFF = invalid

  const float* xb = xyz + (size_t)b * NPTS * 3;
  const int base = j * NPB;

  // stage this block's 12500-point coord slice into LDS (once)
#pragma unroll
  for (int i = 0; i < NPT; ++i) {
    const bool valid = (i < NPT - 1) || (tid < TAIL);
    const int p = tid + i * TPB;
    if (valid) {
      const int gp = base + p;
      sx[p] = xb[gp * 3 + 0];
      sy[p] = xb[gp * 3 + 1];
      sz[p] = xb[gp * 3 + 2];
    }
  }
  // register-resident running min distance; sentinel -1 beyond QTOT
  float pd[NQUAD * 4];
#pragma unroll
  for (int q = 0; q < NQUAD; ++q) {
    const bool vq = (q < NQUAD - 1) || (tid < QTAIL);
#pragma unroll
    for (int k = 0; k < 4; ++k) pd[q * 4 + k] = vq ? 1.0e10f : -1.0f;
  }
  __syncthreads();   // one-time: LDS coords + srel tags ready

  const int cur0 = finit[b];   // int32 delivery (established R8==R5, R1==R2)
  float cx = xb[cur0 * 3 + 0], cy = xb[cur0 * 3 + 1], cz = xb[cur0 * 3 + 2];

  u64* gs = slots + (size_t)b * 2 * NWAVE;   // [parity][wave]

  for (int t = 0; t < NGROUP; ++t) {
    // record current farthest (pre-update); off wave 0's critical path
    if (j == 0 && wid == 1 && lane == 0) {
      float* o = out + ((size_t)b * NGROUP + t) * 3;
      o[0] = cx; o[1] = cy; o[2] = cz;
    }
    if (t == NGROUP - 1) break;   // uniform exit

    const int p   = t & 1;
    const u32 tag = (u32)(t & 0x7FFF);

    // --- distance min-update + thread-local argmax (first-max wins) ---
    float bestv = -1.0f;
    int   besti = 0x7fffffff;
#pragma unroll
    for (int q = 0; q < NQUAD; ++q) {
      int qi = tid + q * TPB;
      if (q == NQUAD - 1 && tid >= QTAIL) qi = 0;   // clamped; pd slots = -1
      const int pb = qi * 4;
      const float4 vx = *(const float4*)&sx[pb];    // ds_read_b128 x3
      const float4 vy = *(const float4*)&sy[pb];
      const float4 vz = *(const float4*)&sz[pb];
#define POINT(K, XK, YK, ZK)                                                  \
      {                                                                       \
        const float dx = fsub_x(XK, cx);                                      \
        const float dy = fsub_x(YK, cy);                                      \
        const float dz = fsub_x(ZK, cz);                                      \
        const float d  = fma_x(dz, dz, fma_x(dy, dy, fmul_x(dx, dx)));        \
        const float nd = fminf(pd[q * 4 + K], d);                             \
        pd[q * 4 + K] = nd;                                                   \
        if (nd > bestv) { bestv = nd; besti = base + pb + K; }                \
      }
      POINT(0, vx.x, vy.x, vz.x)
      POINT(1, vx.y, vy.y, vz.y)
      POINT(2, vx.z, vy.z, vz.z)
      POINT(3, vx.w, vy.w, vz.w)
#undef POINT
    }

    // --- wave-level u64-max reduce, then DIRECT global publish ---
    u64 pk = ((u64)__float_as_uint(bestv) << 32) | (u64)((~(u32)besti) & 0x1FFFFu);
#pragma unroll
    for (int off = 32; off > 0; off >>= 1) {
      const u64 o = __shfl_xor(pk, off, 64);
      if (o > pk) pk = o;
    }
    if (lane == 0) ST_AG(gs + p * NWAVE + gw, pk | ((u64)tag << 17));

    float ncx, ncy, ncz;
    if (wid == 0) {
      // --- poll all 64 wave slots (lane l <-> slot l) ---
      u64 gv;
      do {
        gv = LD_AG(gs + p * NWAVE + lane);
      } while (!__all(((u32)(gv >> 17) & 0x7FFFu) == tag));

      // --- speculative coord prefetch for all 64 candidates (hidden under
      //     the reduce below) ---
      const int cand = (int)((~(u32)gv) & 0x1FFFFu);
      const float* cp = xb + (size_t)cand * 3;
      const float fx = cp[0], fy = cp[1], fz = cp[2];

      u64 win = gv;
#pragma unroll
      for (int off = 32; off > 0; off >>= 1) {
        const u64 o = __shfl_xor(win, off, 64);
        if (o > win) win = o;
      }
      const u64 wmax = __shfl(win, 0, 64);
      const u64 mask = __ballot(gv == wmax);
      const int w    = (int)__ffsll((long long)mask) - 1;
      ncx = __shfl(fx, w, 64); ncy = __shfl(fy, w, 64); ncz = __shfl(fz, w, 64);

      // --- release the block: 3 self-validating tagged LDS words ---
      if (lane == 0) {
        const u64 lo = (u64)tag << 17;
        ST_WG(&srel[p][0], ((u64)__float_as_uint(ncx) << 32) | lo);
        ST_WG(&srel[p][1], ((u64)__float_as_uint(ncy) << 32) | lo);
        ST_WG(&srel[p][2], ((u64)__float_as_uint(ncz) << 32) | lo);
      }
    } else {
      // --- spin on release (runs only while wid0 polls globally; no
      //     concurrent compute to starve) ---
      u64 rv;
      do {
        rv = (lane < 3) ? LD_WG(&srel[p][lane]) : 0ull;
      } while (!__all(lane >= 3 || (((u32)(rv >> 17) & 0x7FFFu) == tag)));
      const float f = __uint_as_float((u32)(rv >> 32));
      ncx = __shfl(f, 0, 64); ncy = __shfl(f, 1, 64); ncz = __shfl(f, 2, 64);
    }

    cx = ncx; cy = ncy; cz = ncz;
  }
}

extern "C" void kernel_launch(void* const* d_in, const int* in_sizes, int n_in,
                              void* d_out, int out_size, void* d_ws, size_t ws_size,
                              hipStream_t stream) {
  const float* xyz   = (const float*)d_in[0];
  const int*   finit = (const int*)d_in[1];
  float*       out   = (float*)d_out;
  u64*         slots = (u64*)d_ws;   // 32 x 2 x 64 u64 = 32 KB exchange slots

  // Invalidate all global slots every call (tag -> 0x7FFF, never valid).
  hipMemsetAsync(d_ws, 0xFF, (size_t)BATCH * 2 * NWAVE * sizeof(u64), stream);

  fps_kernel<<<dim3(BATCH * NBLK_PER_BATCH), dim3(TPB), 0, stream>>>(xyz, finit, out, slots);
}

// Round 26
// 6089.086 us; speedup vs baseline: 1.1631x; 1.1631x over previous
//
#include <hip/hip_runtime.h>

// All ops except the two deliberate FMAs below are per-op rounded.
#pragma clang fp contract(off)

#define BATCH 32
#define NPTS 100000
#define NGROUP 2048
#define NBLK_PER_BATCH 8
#define NPB (NPTS / NBLK_PER_BATCH)   /* 12500 points per block */
#define TPB 512
#define NPT 25                        /* staging: ceil(12500/512) writes/thread */
#define TAIL (NPB - (NPT - 1) * TPB)  /* 212 */
#define NQUAD 7                       /* compute: quads of 4 consecutive pts */
#define QTOT (NPB / 4)                /* 3125 quads, exact */
#define QTAIL (QTOT - (NQUAD - 1) * TPB) /* 53 */

typedef unsigned long long u64;
typedef unsigned int u32;

static_assert(NPB * NBLK_PER_BATCH == NPTS, "block split must be exact");
static_assert(QTOT * 4 == NPB, "quad split must be exact");

__device__ __forceinline__ float fsub_x(float a, float b) {
  float r; asm("v_sub_f32 %0, %1, %2" : "=v"(r) : "v"(a), "v"(b)); return r;
}
__device__ __forceinline__ float fmul_x(float a, float b) {
  float r; asm("v_mul_f32 %0, %1, %2" : "=v"(r) : "v"(a), "v"(b)); return r;
}
__device__ __forceinline__ float fma_x(float a, float b, float c) {
  float r; asm("v_fma_f32 %0, %1, %2, %3" : "=v"(r) : "v"(a), "v"(b), "v"(c)); return r;
}

#define LD_AG(p)    __hip_atomic_load((p),  __ATOMIC_RELAXED, __HIP_MEMORY_SCOPE_AGENT)
#define ST_AG(p,v)  __hip_atomic_store((p), (v), __ATOMIC_RELAXED, __HIP_MEMORY_SCOPE_AGENT)

// R25 post-mortem: per-wave publish (2048 IC stores/iter, 8-line polls)
// recreated the R14/R21 coherence storm. Locked rule: 8 publishers, one
// 64B poll line per batch. This round keeps R24's structure and attacks the
// remaining exchange LATENCY with a dual-path publish:
//  - volatile slot line: L1-bypass, L2-visible. Blocks j*32+b of batch b all
//    map to XCD b%8 under round-robin dispatch (32 = 0 mod 8) -> same L2 ->
//    ~250cyc visibility instead of ~700cyc IC.
//  - agent slot line (as R24): IC-visible, placement-INDEPENDENT guarantee.
// The poller polls both lines (lanes 0-7 agent, 8-15 volatile) and accepts a
// slot from whichever path shows the tag first. If dispatch mapping differs,
// the volatile path is simply late/never and the agent path delivers as in
// R24 — correctness never depends on XCD placement (G16-compliant).
// Slot: distbits[63:32] | tag[31:17] | ~idx[16:0]; memset 0xFF per call.
// Layout per batch: 2 parity x [8 agent u64 | 8 volatile u64] = 256 B.
__global__ __launch_bounds__(TPB, 1)
void fps_kernel(const float* __restrict__ xyz,
                const int* __restrict__ finit,
                float* __restrict__ out,
                u64* __restrict__ slots)
{
  const int blk  = blockIdx.x;
  const int b    = blk & (BATCH - 1);   // batch id
  const int j    = blk >> 5;            // sub-block 0..7 within batch
  const int tid  = threadIdx.x;
  const int lane = tid & 63;
  const int wid  = tid >> 6;

  __shared__ __align__(16) float sx[NPB];   // 50,000 B per plane
  __shared__ __align__(16) float sy[NPB];
  __shared__ __align__(16) float sz[NPB];
  __shared__ u64   sval[8];     // per-wave candidates (barrier-separated)
  __shared__ float scoord[3];   // winner coords (barrier-separated)

  const float* xb = xyz + (size_t)b * NPTS * 3;
  const int base = j * NPB;

  // stage this block's 12500-point coord slice into LDS (once)
#pragma unroll
  for (int i = 0; i < NPT; ++i) {
    const bool valid = (i < NPT - 1) || (tid < TAIL);
    const int p = tid + i * TPB;
    if (valid) {
      const int gp = base + p;
      sx[p] = xb[gp * 3 + 0];
      sy[p] = xb[gp * 3 + 1];
      sz[p] = xb[gp * 3 + 2];
    }
  }
  // register-resident running min distance; sentinel -1 beyond QTOT
  float pd[NQUAD * 4];
#pragma unroll
  for (int q = 0; q < NQUAD; ++q) {
    const bool vq = (q < NQUAD - 1) || (tid < QTAIL);
#pragma unroll
    for (int k = 0; k < 4; ++k) pd[q * 4 + k] = vq ? 1.0e10f : -1.0f;
  }
  __syncthreads();   // LDS coords ready

  const int cur0 = finit[b];   // int32 delivery (established R8==R5, R1==R2)
  float cx = xb[cur0 * 3 + 0], cy = xb[cur0 * 3 + 1], cz = xb[cur0 * 3 + 2];

  u64* gs = slots + (size_t)b * 32;   // [parity][16]: 0-7 agent, 8-15 volatile

  for (int t = 0; t < NGROUP; ++t) {
    // record current farthest (pre-update); off wave 0's critical path
    if (j == 0 && wid == 1 && lane == 0) {
      float* o = out + ((size_t)b * NGROUP + t) * 3;
      o[0] = cx; o[1] = cy; o[2] = cz;
    }
    if (t == NGROUP - 1) break;   // uniform exit

    const int p   = t & 1;
    const u32 tag = (u32)(t & 0x7FFF);
    u64* line = gs + p * 16;

    // --- distance min-update + thread-local argmax (first-max wins) ---
    float bestv = -1.0f;
    int   besti = 0x7fffffff;
#pragma unroll
    for (int q = 0; q < NQUAD; ++q) {
      int qi = tid + q * TPB;
      if (q == NQUAD - 1 && tid >= QTAIL) qi = 0;   // clamped; pd slots = -1
      const int pb = qi * 4;
      const float4 vx = *(const float4*)&sx[pb];    // ds_read_b128 x3
      const float4 vy = *(const float4*)&sy[pb];
      const float4 vz = *(const float4*)&sz[pb];
#define POINT(K, XK, YK, ZK)                                                  \
      {                                                                       \
        const float dx = fsub_x(XK, cx);                                      \
        const float dy = fsub_x(YK, cy);                                      \
        const float dz = fsub_x(ZK, cz);                                      \
        const float d  = fma_x(dz, dz, fma_x(dy, dy, fmul_x(dx, dx)));        \
        const float nd = fminf(pd[q * 4 + K], d);                             \
        pd[q * 4 + K] = nd;                                                   \
        if (nd > bestv) { bestv = nd; besti = base + pb + K; }                \
      }
      POINT(0, vx.x, vy.x, vz.x)
      POINT(1, vx.y, vy.y, vz.y)
      POINT(2, vx.z, vy.z, vz.z)
      POINT(3, vx.w, vy.w, vz.w)
#undef POINT
    }

    // --- wave-level u64-max reduce, post to LDS ---
    u64 pk = ((u64)__float_as_uint(bestv) << 32) | (u64)((~(u32)besti) & 0x1FFFFu);
#pragma unroll
    for (int off = 32; off > 0; off >>= 1) {
      const u64 o = __shfl_xor(pk, off, 64);
      if (o > pk) pk = o;
    }
    if (lane == 0) sval[wid] = pk;
    __syncthreads();   // candidates posted; waiting waves use no LDS BW

    if (wid == 0) {
      // --- reduce 8 wave candidates ---
      u64 sv = (lane < 8) ? sval[lane] : 0ull;
#pragma unroll
      for (int off = 4; off > 0; off >>= 1) {
        const u64 o = __shfl_xor(sv, off, 64);
        if (o > sv) sv = o;
      }
      // --- dual-path publish: volatile (L2 fast path) + agent (IC) ---
      if (lane == 0) {
        const u64 msg = sv | ((u64)tag << 17);
        *(volatile u64*)(line + 8 + j) = msg;   // fast iff co-XCD
        ST_AG(line + j, msg);                   // guaranteed
      }
      // --- poll both lines: lanes 0-7 agent, 8-15 volatile ---
      u64 g = 0;
      u32 okm;
      bool mytk = false;
      do {
        if (lane < 8)        g = LD_AG(line + lane);
        else if (lane < 16)  g = *(volatile u64*)(line + lane);
        mytk = (lane < 16) && (((u32)(g >> 17) & 0x7FFFu) == tag);
        const u64 bal = __ballot(mytk);
        okm = (u32)((bal | (bal >> 8)) & 0xFFu);
      } while (okm != 0xFFu);
      // lanes 0-7: take own value if tagged, else partner lane's (identical)
      const u64 part = __shfl(g, lane + 8, 64);
      u64 gv = 0;
      if (lane < 8) gv = mytk ? g : part;

      // --- speculative coord prefetch for the 8 candidates ---
      float fx = 0.f, fy = 0.f, fz = 0.f;
      if (lane < 8) {
        const int cand = (int)((~(u32)gv) & 0x1FFFFu);
        const float* cp = xb + (size_t)cand * 3;
        fx = cp[0]; fy = cp[1]; fz = cp[2];
      }
      u64 win = gv;   // lanes >= 8 hold 0 (can never win)
#pragma unroll
      for (int off = 4; off > 0; off >>= 1) {
        const u64 o = __shfl_xor(win, off, 64);
        if (o > win) win = o;
      }
      const u64 wmax = __shfl(win, 0, 64);
      const u64 mask = __ballot(lane < 8 && gv == wmax);
      const int w    = (int)__ffsll((long long)mask) - 1;
      const float ncx = __shfl(fx, w, 64);
      const float ncy = __shfl(fy, w, 64);
      const float ncz = __shfl(fz, w, 64);
      if (lane == 0) { scoord[0] = ncx; scoord[1] = ncy; scoord[2] = ncz; }
    }
    __syncthreads();   // winner coords ready

    cx = scoord[0]; cy = scoord[1]; cz = scoord[2];
  }
}

extern "C" void kernel_launch(void* const* d_in, const int* in_sizes, int n_in,
                              void* d_out, int out_size, void* d_ws, size_t ws_size,
                              hipStream_t stream) {
  const float* xyz   = (const float*)d_in[0];
  const int*   finit = (const int*)d_in[1];
  float*       out   = (float*)d_out;
  u64*         slots = (u64*)d_ws;   // 32 batches x 2 parity x 16 u64 = 8 KB

  // Invalidate all slots every call (tag -> 0x7FFF, never valid).
  hipMemsetAsync(d_ws, 0xFF, (size_t)BATCH * 32 * sizeof(u64), stream);

  fps_kernel<<<dim3(BATCH * NBLK_PER_BATCH), dim3(TPB), 0, stream>>>(xyz, finit, out, slots);
}